// Round 15
// baseline (471.223 us; speedup 1.0000x reference)
//
#include <hip/hip_runtime.h>

#define S_LEN 2048
#define HID   4096
#define NHEAD 32
#define DHEAD 128
#define H3    12288

typedef __attribute__((ext_vector_type(8))) __bf16 bf16x8;
typedef __attribute__((ext_vector_type(4))) __bf16 bf16x4;
typedef __attribute__((ext_vector_type(4))) float  f32x4;

__device__ __forceinline__ void gl_lds16(const void* g, void* l) {
  __builtin_amdgcn_global_load_lds(
      (const __attribute__((address_space(1))) void*)g,
      (__attribute__((address_space(3))) void*)l, 16, 0, 0);
}

// ---------------- fp32 -> bf16 elementwise (hidden states) ----------------
__global__ void cvt_f32_bf16(const float* __restrict__ in, __bf16* __restrict__ out, int n4) {
  int i = blockIdx.x * blockDim.x + threadIdx.x;
  if (i >= n4) return;
  float4 v = ((const float4*)in)[i];
  bf16x4 o;
  o.x = (__bf16)v.x; o.y = (__bf16)v.y; o.z = (__bf16)v.z; o.w = (__bf16)v.w;
  ((bf16x4*)out)[i] = o;
}

// ---------------- fp32 [R][C] -> bf16 [C][R] (weight transpose) ----------------
__global__ void transpose_cvt(const float* __restrict__ in, __bf16* __restrict__ out, int R, int C) {
  __shared__ float t[64][65];
  const int tid = threadIdx.x;
  const int r0 = blockIdx.y * 64, c0 = blockIdx.x * 64;
#pragma unroll
  for (int p = 0; p < 4; ++p) {
    int r = p * 16 + (tid >> 4);
    int c4 = (tid & 15) * 4;
    float4 v = *(const float4*)(in + (size_t)(r0 + r) * C + c0 + c4);
    t[r][c4] = v.x; t[r][c4 + 1] = v.y; t[r][c4 + 2] = v.z; t[r][c4 + 3] = v.w;
  }
  __syncthreads();
#pragma unroll
  for (int p = 0; p < 4; ++p) {
    int c = p * 16 + (tid >> 4);
    int rg = (tid & 15) * 4;
    bf16x4 o;
    o.x = (__bf16)t[rg][c]; o.y = (__bf16)t[rg + 1][c];
    o.z = (__bf16)t[rg + 2][c]; o.w = (__bf16)t[rg + 3][c];
    *(bf16x4*)(out + (size_t)(c0 + c) * R + r0 + rg) = o;
  }
}

// ---------------- RoPE in-place on q,k  [NH][S][D]; folds 1/sqrt(d) into q ----------------
__global__ void rope_kernel(__bf16* __restrict__ q, __bf16* __restrict__ k,
                            const int* __restrict__ pos) {
  int idx = blockIdx.x * 256 + threadIdx.x;   // S*NH*64 items
  int j = idx & 63;
  int hs = idx >> 6;
  int s = hs & (S_LEN - 1);
  float p = (float)pos[s];
  float invf = __expf(-(float)j * (9.210340371976184f / 64.f));  // 10000^(-j/64)
  float a = p * invf;
  float c, sn;
  __sincosf(a, &sn, &c);
  const float SC = 0.08838834764831845f;   // 1/sqrt(128), folded into q
  size_t base = (size_t)hs * 128;
  float x1 = (float)q[base + j], x2 = (float)q[base + j + 64];
  q[base + j]      = (__bf16)((x1 * c - x2 * sn) * SC);
  q[base + j + 64] = (__bf16)((x2 * c + x1 * sn) * SC);
  x1 = (float)k[base + j]; x2 = (float)k[base + j + 64];
  k[base + j]      = (__bf16)(x1 * c - x2 * sn);
  k[base + j + 64] = (__bf16)(x2 * c + x1 * sn);
}

// ---------------- 128x128 bf16 GEMM, double-buffered (dense projection) ----------------
__global__ __launch_bounds__(256, 2)
void gemm_dense(const __bf16* __restrict__ A, const __bf16* __restrict__ BT,
                const float* __restrict__ bias, int K,
                float* __restrict__ outf) {
  const int tid = threadIdx.x;
  const int lane = tid & 63;
  const int wave = tid >> 6;
  const int flat = blockIdx.x;
  const int swz = (flat & 7) * 64 + (flat >> 3);   // bijective (512 % 8 == 0)
  const int bm = (swz & 15) * 128;                 // M fastest: 16 blocks share bn
  const int bn = (swz >> 4) * 128;

  __shared__ char lds[2][32768];   // per buf: A 16KB + B 16KB

  f32x4 acc[4][4] = {};

  const int wm = (wave >> 1) * 64;
  const int wn = (wave & 1) * 64;

  const int sr = tid >> 3;
  const int sc = (tid & 7) * 16;
  const int scs = sc ^ ((sr & 7) << 4);   // swizzled source col (LDS stays linear)

  const char* Arow = (const char*)(A + (size_t)(bm + sr) * K) + scs;
  const char* Brow = (const char*)(BT + (size_t)(bn + sr) * K) + scs;

  const int NT = K >> 6;

  auto stage = [&](int t) {
    const char* a_src = Arow + (size_t)t * 128;
    const char* b_src = Brow + (size_t)t * 128;
    char* a_dst = lds[t & 1] + wave * 1024;
    char* b_dst = lds[t & 1] + 16384 + wave * 1024;
#pragma unroll
    for (int i = 0; i < 4; ++i) {
      gl_lds16(a_src + (size_t)i * 32 * K * 2, a_dst + i * 4096);
      gl_lds16(b_src + (size_t)i * 32 * K * 2, b_dst + i * 4096);
    }
  };

  stage(0);
  __syncthreads();
  for (int t = 0; t < NT; ++t) {
    if (t + 1 < NT) stage(t + 1);
    const char* Ab = lds[t & 1];
    const char* Bb = lds[t & 1] + 16384;
#pragma unroll
    for (int kk = 0; kk < 2; ++kk) {
      bf16x8 af[4], bfr[4];
#pragma unroll
      for (int m = 0; m < 4; ++m) {
        int row = wm + m * 16 + (lane & 15);
        int cb = (kk * 64 + ((lane >> 4) << 4)) ^ ((row & 7) << 4);
        af[m] = *(const bf16x8*)(Ab + row * 128 + cb);
      }
#pragma unroll
      for (int n = 0; n < 4; ++n) {
        int row = wn + n * 16 + (lane & 15);
        int cb = (kk * 64 + ((lane >> 4) << 4)) ^ ((row & 7) << 4);
        bfr[n] = *(const bf16x8*)(Bb + row * 128 + cb);
      }
#pragma unroll
      for (int m = 0; m < 4; ++m)
#pragma unroll
        for (int n = 0; n < 4; ++n)
          acc[m][n] = __builtin_amdgcn_mfma_f32_16x16x32_bf16(af[m], bfr[n], acc[m][n], 0, 0, 0);
    }
    __syncthreads();
  }

  const int rbase = (lane >> 4) << 2;
  const int cl = lane & 15;
#pragma unroll
  for (int n = 0; n < 4; ++n) {
    const int col = bn + wn + n * 16 + cl;
    const float bv = bias[col];
#pragma unroll
    for (int m = 0; m < 4; ++m) {
      const int srow = bm + wm + m * 16 + rbase;
#pragma unroll
      for (int r = 0; r < 4; ++r)
        outf[(size_t)(srow + r) * HID + col] = acc[m][n][r] + bv;
    }
  }
}

// ========== 256x128 counted-vmcnt phase GEMM (QKV), 3-slot LDS ring ==========
// 512 thr = 8 waves (4M x 2N), wave tile 64x64, BK=64. Slot = A 32KB + B 16KB = 48KB,
// 3 slots (144KB, 1 blk/CU). Grid 768 = 3x256 exact. Per tile: 2 phases (kk=0/1), each
// {8 ds_read_b128 | stage (t+2) A-or-B | [vmcnt(6) ph1] | barrier | lgkm(0) | 16 MFMA | barrier}.
// FIFO: vmcnt(6) at (t,ph1) retires exactly tile t+1 (A:4 + B:2 newer loads remain).
// Slots: writes -> (t+2)%3, disjoint from read slot t%3 and prefetched (t+1)%3.
__global__ __launch_bounds__(512, 2)
void gemm8p(const __bf16* __restrict__ A, const __bf16* __restrict__ BT,
            const float* __restrict__ bias, int K,
            __bf16* __restrict__ outq, __bf16* __restrict__ outk,
            __bf16* __restrict__ outvt) {
  const int tid = threadIdx.x, lane = tid & 63, wave = tid >> 6;
  const int flat = blockIdx.x;
  const int swz = (flat & 7) * 96 + (flat >> 3);   // bijective (768 % 8 == 0)
  const int bm = (swz & 7) * 256;
  const int bn = (swz >> 3) * 128;

  __shared__ char lds[3 * 49152];

  const int widM = wave >> 1, widN = wave & 1;
  const int cl = lane & 15;
  const int hi16 = (lane >> 4) << 4;
  const int rbase = (lane >> 4) << 2;

  const int K2 = K * 2;
  const int sr = tid >> 3;                               // 0..63
  const int scs = ((tid & 7) * 16) ^ ((sr & 7) << 4);    // pre-swizzled source col-byte
  const char* Asrc = (const char*)A + (size_t)(bm + sr) * K2 + scs;
  const char* Bsrc = (const char*)BT + (size_t)(bn + sr) * K2 + scs;

  f32x4 acc[4][4] = {};
  const int NT = K >> 6;

  auto stageA = [&](int t) {      // 4 gl_lds16/thread: A rows 0..255
    char* d = lds + (t % 3) * 49152 + wave * 1024;
    const char* s = Asrc + (size_t)t * 128;
#pragma unroll
    for (int i = 0; i < 4; ++i)
      gl_lds16(s + (size_t)(i * 64) * K2, d + i * 8192);
  };
  auto stageB = [&](int t) {      // 2 gl_lds16/thread: B rows 0..127
    char* d = lds + (t % 3) * 49152 + 32768 + wave * 1024;
    const char* s = Bsrc + (size_t)t * 128;
#pragma unroll
    for (int i = 0; i < 2; ++i)
      gl_lds16(s + (size_t)(i * 64) * K2, d + i * 8192);
  };

  // prologue: tiles 0 and 1 (12 loads); retire tile 0 (oldest 6)
  stageA(0); stageB(0); stageA(1); stageB(1);
  asm volatile("s_waitcnt vmcnt(6)" ::: "memory");
  asm volatile("s_barrier" ::: "memory");

  for (int t = 0; t < NT; ++t) {
    const char* sA = lds + (t % 3) * 49152;
    const char* sB = sA + 32768;
    // ---- phase 0: kk = 0 ----
    {
      bf16x8 af[4], bfr[4];
#pragma unroll
      for (int m = 0; m < 4; ++m) {
        const int row = widM * 64 + m * 16 + cl;
        af[m] = *(const bf16x8*)(sA + row * 128 + (hi16 ^ ((row & 7) << 4)));
      }
#pragma unroll
      for (int n = 0; n < 4; ++n) {
        const int row = widN * 64 + n * 16 + cl;
        bfr[n] = *(const bf16x8*)(sB + row * 128 + (hi16 ^ ((row & 7) << 4)));
      }
      if (t + 2 < NT) stageA(t + 2);
      asm volatile("s_barrier" ::: "memory");
      asm volatile("s_waitcnt lgkmcnt(0)" ::: "memory");
      __builtin_amdgcn_s_setprio(1);
#pragma unroll
      for (int m = 0; m < 4; ++m)
#pragma unroll
        for (int n = 0; n < 4; ++n)
          acc[m][n] = __builtin_amdgcn_mfma_f32_16x16x32_bf16(af[m], bfr[n], acc[m][n], 0, 0, 0);
      __builtin_amdgcn_s_setprio(0);
      asm volatile("s_barrier" ::: "memory");
    }
    // ---- phase 1: kk = 1 ----
    {
      bf16x8 af[4], bfr[4];
#pragma unroll
      for (int m = 0; m < 4; ++m) {
        const int row = widM * 64 + m * 16 + cl;
        af[m] = *(const bf16x8*)(sA + row * 128 + ((64 + hi16) ^ ((row & 7) << 4)));
      }
#pragma unroll
      for (int n = 0; n < 4; ++n) {
        const int row = widN * 64 + n * 16 + cl;
        bfr[n] = *(const bf16x8*)(sB + row * 128 + ((64 + hi16) ^ ((row & 7) << 4)));
      }
      if (t + 2 < NT) {
        stageB(t + 2);
        asm volatile("s_waitcnt vmcnt(6)" ::: "memory");   // retires tile t+1 exactly
      } else {
        asm volatile("s_waitcnt vmcnt(0)" ::: "memory");   // tail drain
      }
      asm volatile("s_barrier" ::: "memory");
      asm volatile("s_waitcnt lgkmcnt(0)" ::: "memory");
      __builtin_amdgcn_s_setprio(1);
#pragma unroll
      for (int m = 0; m < 4; ++m)
#pragma unroll
        for (int n = 0; n < 4; ++n)
          acc[m][n] = __builtin_amdgcn_mfma_f32_16x16x32_bf16(af[m], bfr[n], acc[m][n], 0, 0, 0);
      __builtin_amdgcn_s_setprio(0);
      asm volatile("s_barrier" ::: "memory");
    }
  }

  // epilogue: bias + route to q/k/vt (BN=128 aligns with route blocks)
  const int route = (bn >> 7) % 3;
  const int head = bn / 384;
#pragma unroll
  for (int n = 0; n < 4; ++n) {
    const int d = widN * 64 + n * 16 + cl;        // 0..127 within block
    const float bv = bias[bn + d];
#pragma unroll
    for (int m = 0; m < 4; ++m) {
      const int srow = bm + widM * 64 + m * 16 + rbase;
      if (route == 2) {
        bf16x4 o;
        o.x = (__bf16)(acc[m][n][0] + bv);
        o.y = (__bf16)(acc[m][n][1] + bv);
        o.z = (__bf16)(acc[m][n][2] + bv);
        o.w = (__bf16)(acc[m][n][3] + bv);
        *(bf16x4*)(outvt + ((size_t)head * 128 + d) * S_LEN + srow) = o;
      } else {
        __bf16* dst = (route == 0 ? outq : outk) + (size_t)head * S_LEN * 128;
#pragma unroll
        for (int r = 0; r < 4; ++r)
          dst[(size_t)(srow + r) * 128 + d] = (__bf16)(acc[m][n][r] + bv);
      }
    }
  }
}

// ---------------- flash attention (causal), paired q-tiles with SHARED staging ----------------
// 1D grid 512, XCD-chunked swizzle: 64 consecutive swz = 4 whole heads per XCD.
// T5: setprio(1) around MFMA clusters.
#define ATTN_PROCESS(QF, OACC, MROW, LROW, QT)                                  \
  {                                                                             \
    f32x4 sacc[4] = {};                                                         \
    _Pragma("unroll")                                                           \
    for (int kk = 0; kk < 4; ++kk) {                                            \
      bf16x8 bk[4];                                                             \
      _Pragma("unroll")                                                         \
      for (int n = 0; n < 4; ++n) {                                             \
        int row = n * 16 + cl;                                                  \
        int cb = (kk * 64 + ((lane >> 4) << 4)) ^ ((row & 7) << 4);             \
        bk[n] = *(const bf16x8*)(Kb + row * 256 + cb);                          \
      }                                                                         \
      __builtin_amdgcn_s_setprio(1);                                            \
      _Pragma("unroll")                                                         \
      for (int n = 0; n < 4; ++n)                                               \
        sacc[n] = __builtin_amdgcn_mfma_f32_16x16x32_bf16(QF[kk], bk[n], sacc[n], 0, 0, 0); \
      __builtin_amdgcn_s_setprio(0);                                            \
    }                                                                           \
    float pmax[4];                                                              \
    _Pragma("unroll")                                                           \
    for (int r = 0; r < 4; ++r) pmax[r] = -1e30f;                               \
    if (j == (QT)) {                                                            \
      _Pragma("unroll")                                                         \
      for (int n = 0; n < 4; ++n) {                                             \
        const int col = n * 16 + cl;                                            \
        _Pragma("unroll")                                                       \
        for (int r = 0; r < 4; ++r) {                                           \
          const int row = wave * 16 + rbase + r;                                \
          float sv = (col > row) ? -1e30f : sacc[n][r];                         \
          sacc[n][r] = sv;                                                      \
          pmax[r] = fmaxf(pmax[r], sv);                                         \
        }                                                                       \
      }                                                                         \
    } else {                                                                    \
      _Pragma("unroll")                                                         \
      for (int n = 0; n < 4; ++n)                                               \
        _Pragma("unroll")                                                       \
        for (int r = 0; r < 4; ++r)                                             \
          pmax[r] = fmaxf(pmax[r], sacc[n][r]);                                 \
    }                                                                           \
    _Pragma("unroll")                                                           \
    for (int xm = 1; xm < 16; xm <<= 1)                                         \
      _Pragma("unroll")                                                         \
      for (int r = 0; r < 4; ++r)                                               \
        pmax[r] = fmaxf(pmax[r], __shfl_xor(pmax[r], xm, 64));                  \
    const bool okd = (pmax[0] <= MROW[0] + 8.f) && (pmax[1] <= MROW[1] + 8.f) && \
                     (pmax[2] <= MROW[2] + 8.f) && (pmax[3] <= MROW[3] + 8.f);  \
    if (__all(okd)) {                                                           \
      _Pragma("unroll")                                                         \
      for (int r = 0; r < 4; ++r) {                                             \
        float psum = 0.f;                                                       \
        _Pragma("unroll")                                                       \
        for (int n = 0; n < 4; ++n) {                                           \
          float pe = __expf(sacc[n][r] - MROW[r]);                              \
          sacc[n][r] = pe;                                                      \
          psum += pe;                                                           \
        }                                                                       \
        _Pragma("unroll")                                                       \
        for (int xm = 1; xm < 16; xm <<= 1)                                     \
          psum += __shfl_xor(psum, xm, 64);                                     \
        LROW[r] += psum;                                                        \
      }                                                                         \
    } else {                                                                    \
      _Pragma("unroll")                                                         \
      for (int r = 0; r < 4; ++r) {                                             \
        const float mnew = fmaxf(MROW[r], pmax[r]);                             \
        const float alpha = __expf(MROW[r] - mnew);                             \
        MROW[r] = mnew;                                                         \
        float psum = 0.f;                                                       \
        _Pragma("unroll")                                                       \
        for (int n = 0; n < 4; ++n) {                                           \
          float pe = __expf(sacc[n][r] - mnew);                                 \
          sacc[n][r] = pe;                                                      \
          psum += pe;                                                           \
        }                                                                       \
        _Pragma("unroll")                                                       \
        for (int xm = 1; xm < 16; xm <<= 1)                                     \
          psum += __shfl_xor(psum, xm, 64);                                     \
        LROW[r] = LROW[r] * alpha + psum;                                       \
        _Pragma("unroll")                                                       \
        for (int nd = 0; nd < 8; ++nd)                                          \
          OACC[nd][r] *= alpha;                                                 \
      }                                                                         \
    }                                                                           \
    _Pragma("unroll")                                                           \
    for (int n = 0; n < 4; ++n) {                                               \
      const int colb = (n * 16 + cl) * 2;                                       \
      _Pragma("unroll")                                                         \
      for (int r = 0; r < 4; ++r) {                                             \
        const int row = rbase + r;                                              \
        *(__bf16*)(Pb + row * 128 + (colb ^ ((row & 7) << 4))) = (__bf16)sacc[n][r]; \
      }                                                                         \
    }                                                                           \
    _Pragma("unroll")                                                           \
    for (int kk = 0; kk < 2; ++kk) {                                            \
      bf16x8 pa, bv[8];                                                         \
      {                                                                         \
        int row = cl;                                                           \
        int cb = (kk * 64 + ((lane >> 4) << 4)) ^ ((row & 7) << 4);             \
        pa = *(const bf16x8*)(Pb + row * 128 + cb);                             \
      }                                                                         \
      _Pragma("unroll")                                                         \
      for (int nd = 0; nd < 8; ++nd) {                                          \
        int row = nd * 16 + cl;                                                 \
        int cb = (kk * 64 + ((lane >> 4) << 4)) ^ ((row & 7) << 4);             \
        bv[nd] = *(const bf16x8*)(Vb + row * 128 + cb);                         \
      }                                                                         \
      __builtin_amdgcn_s_setprio(1);                                            \
      _Pragma("unroll")                                                         \
      for (int nd = 0; nd < 8; ++nd)                                            \
        OACC[nd] = __builtin_amdgcn_mfma_f32_16x16x32_bf16(pa, bv[nd], OACC[nd], 0, 0, 0); \
      __builtin_amdgcn_s_setprio(0);                                            \
    }                                                                           \
  }

__global__ __launch_bounds__(256, 2)
void attn_kernel(const __bf16* __restrict__ q, const __bf16* __restrict__ k,
                 const __bf16* __restrict__ vt, __bf16* __restrict__ ctx) {
  const int flat = blockIdx.x;
  const int swz = (flat & 7) * 64 + (flat >> 3);   // bijective (512 % 8 == 0)
  const int p = swz & 15;                          // q-pair index
  const int h = swz >> 4;                          // head: 4 heads per XCD chunk
  const int tid = threadIdx.x, lane = tid & 63, wave = tid >> 6;
  __shared__ char Kd[2][16384];       // K [kv64][d128] bf16, 256B rows
  __shared__ char Vd[2][16384];       // V^T [d128][kv64] bf16, 128B rows
  __shared__ __bf16 Ps[4][16 * 64];   // per-wave P (16 q-rows x 64 kv), 128B rows
  char* Pb = (char*)(Ps[wave]);

  const __bf16* qh = q + (size_t)h * S_LEN * 128;
  const __bf16* kh = k + (size_t)h * S_LEN * 128;
  const __bf16* vh = vt + (size_t)h * 128 * S_LEN;

  const int cl = lane & 15, rbase = (lane >> 4) << 2;

  const int krow = tid >> 4, kcol = (tid & 15) * 16;
  const int kcs = kcol ^ ((krow & 7) << 4);
  const int vrow = tid >> 3, vcol = (tid & 7) * 16;
  const int vcs = vcol ^ ((vrow & 7) << 4);

  auto stage_kv = [&](int j) {
    {
      const char* src = (const char*)(kh + (size_t)(j * 64 + krow) * 128) + kcs;
      char* dst = Kd[j & 1] + wave * 1024;
#pragma unroll
      for (int i = 0; i < 4; ++i)
        gl_lds16(src + (size_t)i * 16 * 256, dst + i * 4096);
    }
    {
      const char* src = (const char*)(vh + (size_t)vrow * S_LEN + j * 64) + vcs;
      char* dst = Vd[j & 1] + wave * 1024;
#pragma unroll
      for (int i = 0; i < 4; ++i)
        gl_lds16(src + (size_t)i * 32 * (S_LEN * 2), dst + i * 4096);
    }
  };

  const int qtA = p, qtB = 31 - p;

  bf16x8 qfA[4], qfB[4];
  {
    const int rA = qtA * 64 + wave * 16 + cl;
    const int rB = qtB * 64 + wave * 16 + cl;
#pragma unroll
    for (int kk = 0; kk < 4; ++kk) {
      qfA[kk] = *(const bf16x8*)(qh + (size_t)rA * 128 + kk * 32 + ((lane >> 4) << 3));
      qfB[kk] = *(const bf16x8*)(qh + (size_t)rB * 128 + kk * 32 + ((lane >> 4) << 3));
    }
  }

  f32x4 oA[8] = {}, oB[8] = {};
  float mA[4], lA[4], mB[4], lB[4];
#pragma unroll
  for (int r = 0; r < 4; ++r) { mA[r] = -1e30f; lA[r] = 0.f; mB[r] = -1e30f; lB[r] = 0.f; }

  stage_kv(0);
  __syncthreads();
  for (int j = 0; j <= qtB; ++j) {
    if (j < qtB) stage_kv(j + 1);   // prefetch buf^1, hides under compute(s)
    const char* Kb = Kd[j & 1];
    const char* Vb = Vd[j & 1];
    ATTN_PROCESS(qfB, oB, mB, lB, qtB)
    if (j <= qtA) ATTN_PROCESS(qfA, oA, mA, lA, qtA)
    __syncthreads();
  }

  // epilogues
#pragma unroll
  for (int nd = 0; nd < 8; ++nd) {
    const int d = nd * 16 + cl;
#pragma unroll
    for (int r = 0; r < 4; ++r) {
      const int srowA = qtA * 64 + wave * 16 + rbase + r;
      const int srowB = qtB * 64 + wave * 16 + rbase + r;
      ctx[(size_t)srowA * HID + h * 128 + d] = (__bf16)(oA[nd][r] / lA[r]);
      ctx[(size_t)srowB * HID + h * 128 + d] = (__bf16)(oB[nd][r] / lB[r]);
    }
  }
}

extern "C" void kernel_launch(void* const* d_in, const int* in_sizes, int n_in,
                              void* d_out, int out_size, void* d_ws, size_t ws_size,
                              hipStream_t stream) {
  const float* hs = (const float*)d_in[0];
  const int* pos = (const int*)d_in[1];
  const float* wqkv = (const float*)d_in[3];
  const float* bqkv = (const float*)d_in[4];
  const float* wd = (const float*)d_in[5];
  const float* bd = (const float*)d_in[6];
  float* out = (float*)d_out;

  char* ws = (char*)d_ws;
  const size_t MB = 1024ull * 1024ull;
  if (ws_size < 160 * MB) return;   // need 160MB scratch
  __bf16* wT  = (__bf16*)(ws);             // 96MB: wqkv^T bf16 [12288][4096]; later wdense^T
  __bf16* xb  = (__bf16*)(ws + 96 * MB);   // 16MB: x bf16; later ctx bf16
  __bf16* qb_ = (__bf16*)(ws + 112 * MB);  // 16MB: q [NH][S][D]
  __bf16* kb_ = (__bf16*)(ws + 128 * MB);  // 16MB: k [NH][S][D]
  __bf16* vtb = (__bf16*)(ws + 144 * MB);  // 16MB: v^T [NH][D][S]

  cvt_f32_bf16<<<8192, 256, 0, stream>>>(hs, xb, 2097152);
  transpose_cvt<<<dim3(192, 64), 256, 0, stream>>>(wqkv, wT, 4096, 12288);
  gemm8p<<<768, 512, 0, stream>>>(xb, wT, bqkv, 4096, qb_, kb_, vtb);
  rope_kernel<<<16384, 256, 0, stream>>>(qb_, kb_, pos);
  transpose_cvt<<<dim3(64, 64), 256, 0, stream>>>(wd, wT, 4096, 4096);
  attn_kernel<<<512, 256, 0, stream>>>(qb_, kb_, vtb, xb);
  gemm_dense<<<512, 256, 0, stream>>>(xb, wT, bd, 4096, out);
}

// Round 16
// 450.219 us; speedup vs baseline: 1.0467x; 1.0467x over previous
//
#include <hip/hip_runtime.h>

#define S_LEN 2048
#define HID   4096
#define NHEAD 32
#define DHEAD 128
#define H3    12288

typedef __attribute__((ext_vector_type(8))) __bf16 bf16x8;
typedef __attribute__((ext_vector_type(4))) __bf16 bf16x4;
typedef __attribute__((ext_vector_type(4))) float  f32x4;
typedef __attribute__((ext_vector_type(16))) float f32x16;

__device__ __forceinline__ void gl_lds16(const void* g, void* l) {
  __builtin_amdgcn_global_load_lds(
      (const __attribute__((address_space(1))) void*)g,
      (__attribute__((address_space(3))) void*)l, 16, 0, 0);
}

// ---------------- fp32 -> bf16 elementwise (hidden states) ----------------
__global__ void cvt_f32_bf16(const float* __restrict__ in, __bf16* __restrict__ out, int n4) {
  int i = blockIdx.x * blockDim.x + threadIdx.x;
  if (i >= n4) return;
  float4 v = ((const float4*)in)[i];
  bf16x4 o;
  o.x = (__bf16)v.x; o.y = (__bf16)v.y; o.z = (__bf16)v.z; o.w = (__bf16)v.w;
  ((bf16x4*)out)[i] = o;
}

// ---------------- fp32 [R][C] -> bf16 [C][R] (weight transpose) ----------------
__global__ void transpose_cvt(const float* __restrict__ in, __bf16* __restrict__ out, int R, int C) {
  __shared__ float t[64][65];
  const int tid = threadIdx.x;
  const int r0 = blockIdx.y * 64, c0 = blockIdx.x * 64;
#pragma unroll
  for (int p = 0; p < 4; ++p) {
    int r = p * 16 + (tid >> 4);
    int c4 = (tid & 15) * 4;
    float4 v = *(const float4*)(in + (size_t)(r0 + r) * C + c0 + c4);
    t[r][c4] = v.x; t[r][c4 + 1] = v.y; t[r][c4 + 2] = v.z; t[r][c4 + 3] = v.w;
  }
  __syncthreads();
#pragma unroll
  for (int p = 0; p < 4; ++p) {
    int c = p * 16 + (tid >> 4);
    int rg = (tid & 15) * 4;
    bf16x4 o;
    o.x = (__bf16)t[rg][c]; o.y = (__bf16)t[rg + 1][c];
    o.z = (__bf16)t[rg + 2][c]; o.w = (__bf16)t[rg + 3][c];
    *(bf16x4*)(out + (size_t)(c0 + c) * R + r0 + rg) = o;
  }
}

// ---------------- RoPE in-place on q,k  [NH][S][D]; folds 1/sqrt(d) into q ----------------
__global__ void rope_kernel(__bf16* __restrict__ q, __bf16* __restrict__ k,
                            const int* __restrict__ pos) {
  int idx = blockIdx.x * 256 + threadIdx.x;   // S*NH*64 items
  int j = idx & 63;
  int hs = idx >> 6;
  int s = hs & (S_LEN - 1);
  float p = (float)pos[s];
  float invf = __expf(-(float)j * (9.210340371976184f / 64.f));  // 10000^(-j/64)
  float a = p * invf;
  float c, sn;
  __sincosf(a, &sn, &c);
  const float SC = 0.08838834764831845f;   // 1/sqrt(128), folded into q
  size_t base = (size_t)hs * 128;
  float x1 = (float)q[base + j], x2 = (float)q[base + j + 64];
  q[base + j]      = (__bf16)((x1 * c - x2 * sn) * SC);
  q[base + j + 64] = (__bf16)((x2 * c + x1 * sn) * SC);
  x1 = (float)k[base + j]; x2 = (float)k[base + j + 64];
  k[base + j]      = (__bf16)(x1 * c - x2 * sn);
  k[base + j + 64] = (__bf16)(x2 * c + x1 * sn);
}

// ---------------- 128x128 bf16 GEMM, double-buffered (dense projection) ----------------
// 1D grid 512, XCD-chunked swizzle: 64 consecutive swz (4 B-panels) per XCD.
__global__ __launch_bounds__(256, 2)
void gemm_dense(const __bf16* __restrict__ A, const __bf16* __restrict__ BT,
                const float* __restrict__ bias, int K,
                float* __restrict__ outf) {
  const int tid = threadIdx.x;
  const int lane = tid & 63;
  const int wave = tid >> 6;
  const int flat = blockIdx.x;
  const int swz = (flat & 7) * 64 + (flat >> 3);   // bijective (512 % 8 == 0)
  const int bm = (swz & 15) * 128;                 // M fastest: 16 blocks share bn
  const int bn = (swz >> 4) * 128;

  __shared__ char lds[2][32768];   // per buf: A 16KB + B 16KB

  f32x4 acc[4][4] = {};

  const int wm = (wave >> 1) * 64;
  const int wn = (wave & 1) * 64;

  const int sr = tid >> 3;
  const int sc = (tid & 7) * 16;
  const int scs = sc ^ ((sr & 7) << 4);   // swizzled source col (LDS stays linear)

  const char* Arow = (const char*)(A + (size_t)(bm + sr) * K) + scs;
  const char* Brow = (const char*)(BT + (size_t)(bn + sr) * K) + scs;

  const int NT = K >> 6;

  auto stage = [&](int t) {
    const char* a_src = Arow + (size_t)t * 128;
    const char* b_src = Brow + (size_t)t * 128;
    char* a_dst = lds[t & 1] + wave * 1024;
    char* b_dst = lds[t & 1] + 16384 + wave * 1024;
#pragma unroll
    for (int i = 0; i < 4; ++i) {
      gl_lds16(a_src + (size_t)i * 32 * K * 2, a_dst + i * 4096);
      gl_lds16(b_src + (size_t)i * 32 * K * 2, b_dst + i * 4096);
    }
  };

  stage(0);
  __syncthreads();
  for (int t = 0; t < NT; ++t) {
    if (t + 1 < NT) stage(t + 1);
    const char* Ab = lds[t & 1];
    const char* Bb = lds[t & 1] + 16384;
#pragma unroll
    for (int kk = 0; kk < 2; ++kk) {
      bf16x8 af[4], bfr[4];
#pragma unroll
      for (int m = 0; m < 4; ++m) {
        int row = wm + m * 16 + (lane & 15);
        int cb = (kk * 64 + ((lane >> 4) << 4)) ^ ((row & 7) << 4);
        af[m] = *(const bf16x8*)(Ab + row * 128 + cb);
      }
#pragma unroll
      for (int n = 0; n < 4; ++n) {
        int row = wn + n * 16 + (lane & 15);
        int cb = (kk * 64 + ((lane >> 4) << 4)) ^ ((row & 7) << 4);
        bfr[n] = *(const bf16x8*)(Bb + row * 128 + cb);
      }
#pragma unroll
      for (int m = 0; m < 4; ++m)
#pragma unroll
        for (int n = 0; n < 4; ++n)
          acc[m][n] = __builtin_amdgcn_mfma_f32_16x16x32_bf16(af[m], bfr[n], acc[m][n], 0, 0, 0);
    }
    __syncthreads();
  }

  const int rbase = (lane >> 4) << 2;
  const int cl = lane & 15;
#pragma unroll
  for (int n = 0; n < 4; ++n) {
    const int col = bn + wn + n * 16 + cl;
    const float bv = bias[col];
#pragma unroll
    for (int m = 0; m < 4; ++m) {
      const int srow = bm + wm + m * 16 + rbase;
#pragma unroll
      for (int r = 0; r < 4; ++r)
        outf[(size_t)(srow + r) * HID + col] = acc[m][n][r] + bv;
    }
  }
}

// ---------------- 256x128 bf16 GEMM, 32x32x16 MFMA (QKV only) ----------------
// 1D grid 768, XCD-chunked swizzle: bm fastest (8 same-bn blocks share B-panel per L2).
template <int EPI>
__global__ __launch_bounds__(256, 2)
void gemm32(const __bf16* __restrict__ A, const __bf16* __restrict__ BT,
            const float* __restrict__ bias, int K,
            __bf16* __restrict__ outq, __bf16* __restrict__ outk,
            __bf16* __restrict__ outvt) {
  const int tid = threadIdx.x;
  const int lane = tid & 63;
  const int wave = tid >> 6;
  const int flat = blockIdx.x;
  const int swz = (flat & 7) * 96 + (flat >> 3);   // bijective (768 % 8 == 0)
  const int bm = (swz & 7) * 256;
  const int bn = (swz >> 3) * 128;

  __shared__ char lds[49152];          // A 32KB [256][64] + B 16KB [128][64]
  char* Ab = lds;
  char* Bb = lds + 32768;

  f32x16 acc[4][2] = {};

  const int wm = (wave >> 1) * 128;    // M-half
  const int wn = (wave & 1) * 64;      // N-half
  const int l31 = lane & 31;
  const int hi = lane >> 5;

  const int sr = tid >> 3;
  const int scb = ((tid & 7) * 16) ^ ((sr & 7) << 4);   // swizzled source col-byte
  const int K2 = K * 2;
  const char* Arow = (const char*)A + (size_t)(bm + sr) * K2 + scb;
  const char* Brow = (const char*)BT + (size_t)(bn + sr) * K2 + scb;

  for (int k0 = 0; k0 < K; k0 += 64) {
    const char* a_src = Arow + (size_t)k0 * 2;
    const char* b_src = Brow + (size_t)k0 * 2;
    char* a_dst = Ab + wave * 1024;
    char* b_dst = Bb + wave * 1024;
#pragma unroll
    for (int i = 0; i < 8; ++i)
      gl_lds16(a_src + (size_t)i * 32 * K2, a_dst + i * 4096);
#pragma unroll
    for (int i = 0; i < 4; ++i)
      gl_lds16(b_src + (size_t)i * 32 * K2, b_dst + i * 4096);
    __syncthreads();
#pragma unroll
    for (int kk = 0; kk < 4; ++kk) {
      const int cbase = kk * 32 + (hi << 4);
      bf16x8 af[4], bfr[2];
#pragma unroll
      for (int m = 0; m < 4; ++m) {
        const int row = wm + m * 32 + l31;
        af[m] = *(const bf16x8*)(Ab + row * 128 + (cbase ^ ((row & 7) << 4)));
      }
#pragma unroll
      for (int n = 0; n < 2; ++n) {
        const int row = wn + n * 32 + l31;
        bfr[n] = *(const bf16x8*)(Bb + row * 128 + (cbase ^ ((row & 7) << 4)));
      }
#pragma unroll
      for (int m = 0; m < 4; ++m)
#pragma unroll
        for (int n = 0; n < 2; ++n)
          acc[m][n] = __builtin_amdgcn_mfma_f32_32x32x16_bf16(af[m], bfr[n], acc[m][n], 0, 0, 0);
    }
    __syncthreads();
  }

  // C/D mapping (32x32): col = lane&31, row = (r&3) + 8*(r>>2) + 4*(lane>>5)
  const int route = (bn >> 7) % 3;   // 0=q 1=k 2=v (tiles align: 384 = 3*128)
  const int head = bn / 384;
#pragma unroll
  for (int n = 0; n < 2; ++n) {
    const int d = wn + n * 32 + l31;           // 0..127 within block
    const float bv = bias[bn + d];
#pragma unroll
    for (int m = 0; m < 4; ++m) {
      if (route == 2) {
#pragma unroll
        for (int qd = 0; qd < 4; ++qd) {
          const int srow = bm + wm + m * 32 + qd * 8 + (hi << 2);
          bf16x4 o;
          o.x = (__bf16)(acc[m][n][qd * 4 + 0] + bv);
          o.y = (__bf16)(acc[m][n][qd * 4 + 1] + bv);
          o.z = (__bf16)(acc[m][n][qd * 4 + 2] + bv);
          o.w = (__bf16)(acc[m][n][qd * 4 + 3] + bv);
          *(bf16x4*)(outvt + ((size_t)head * 128 + d) * S_LEN + srow) = o;
        }
      } else {
        __bf16* dst = (route == 0 ? outq : outk) + (size_t)head * S_LEN * 128;
#pragma unroll
        for (int r = 0; r < 16; ++r) {
          const int srow = bm + wm + m * 32 + (r & 3) + 8 * (r >> 2) + (hi << 2);
          dst[(size_t)srow * 128 + d] = (__bf16)(acc[m][n][r] + bv);
        }
      }
    }
  }
}

// ---------------- flash attention (causal), paired q-tiles with SHARED staging ----------------
// 1D grid 512, XCD-chunked swizzle: 64 consecutive swz = 4 whole heads per XCD.
// T5: setprio(1) around MFMA clusters (2 independent blocks/CU -> m191 regime).
#define ATTN_PROCESS(QF, OACC, MROW, LROW, QT)                                  \
  {                                                                             \
    f32x4 sacc[4] = {};                                                         \
    _Pragma("unroll")                                                           \
    for (int kk = 0; kk < 4; ++kk) {                                            \
      bf16x8 bk[4];                                                             \
      _Pragma("unroll")                                                         \
      for (int n = 0; n < 4; ++n) {                                             \
        int row = n * 16 + cl;                                                  \
        int cb = (kk * 64 + ((lane >> 4) << 4)) ^ ((row & 7) << 4);             \
        bk[n] = *(const bf16x8*)(Kb + row * 256 + cb);                          \
      }                                                                         \
      __builtin_amdgcn_s_setprio(1);                                            \
      _Pragma("unroll")                                                         \
      for (int n = 0; n < 4; ++n)                                               \
        sacc[n] = __builtin_amdgcn_mfma_f32_16x16x32_bf16(QF[kk], bk[n], sacc[n], 0, 0, 0); \
      __builtin_amdgcn_s_setprio(0);                                            \
    }                                                                           \
    float pmax[4];                                                              \
    _Pragma("unroll")                                                           \
    for (int r = 0; r < 4; ++r) pmax[r] = -1e30f;                               \
    if (j == (QT)) {                                                            \
      _Pragma("unroll")                                                         \
      for (int n = 0; n < 4; ++n) {                                             \
        const int col = n * 16 + cl;                                            \
        _Pragma("unroll")                                                       \
        for (int r = 0; r < 4; ++r) {                                           \
          const int row = wave * 16 + rbase + r;                                \
          float sv = (col > row) ? -1e30f : sacc[n][r];                         \
          sacc[n][r] = sv;                                                      \
          pmax[r] = fmaxf(pmax[r], sv);                                         \
        }                                                                       \
      }                                                                         \
    } else {                                                                    \
      _Pragma("unroll")                                                         \
      for (int n = 0; n < 4; ++n)                                               \
        _Pragma("unroll")                                                       \
        for (int r = 0; r < 4; ++r)                                             \
          pmax[r] = fmaxf(pmax[r], sacc[n][r]);                                 \
    }                                                                           \
    _Pragma("unroll")                                                           \
    for (int xm = 1; xm < 16; xm <<= 1)                                         \
      _Pragma("unroll")                                                         \
      for (int r = 0; r < 4; ++r)                                               \
        pmax[r] = fmaxf(pmax[r], __shfl_xor(pmax[r], xm, 64));                  \
    const bool okd = (pmax[0] <= MROW[0] + 8.f) && (pmax[1] <= MROW[1] + 8.f) && \
                     (pmax[2] <= MROW[2] + 8.f) && (pmax[3] <= MROW[3] + 8.f);  \
    if (__all(okd)) {                                                           \
      _Pragma("unroll")                                                         \
      for (int r = 0; r < 4; ++r) {                                             \
        float psum = 0.f;                                                       \
        _Pragma("unroll")                                                       \
        for (int n = 0; n < 4; ++n) {                                           \
          float pe = __expf(sacc[n][r] - MROW[r]);                              \
          sacc[n][r] = pe;                                                      \
          psum += pe;                                                           \
        }                                                                       \
        _Pragma("unroll")                                                       \
        for (int xm = 1; xm < 16; xm <<= 1)                                     \
          psum += __shfl_xor(psum, xm, 64);                                     \
        LROW[r] += psum;                                                        \
      }                                                                         \
    } else {                                                                    \
      _Pragma("unroll")                                                         \
      for (int r = 0; r < 4; ++r) {                                             \
        const float mnew = fmaxf(MROW[r], pmax[r]);                             \
        const float alpha = __expf(MROW[r] - mnew);                             \
        MROW[r] = mnew;                                                         \
        float psum = 0.f;                                                       \
        _Pragma("unroll")                                                       \
        for (int n = 0; n < 4; ++n) {                                           \
          float pe = __expf(sacc[n][r] - mnew);                                 \
          sacc[n][r] = pe;                                                      \
          psum += pe;                                                           \
        }                                                                       \
        _Pragma("unroll")                                                       \
        for (int xm = 1; xm < 16; xm <<= 1)                                     \
          psum += __shfl_xor(psum, xm, 64);                                     \
        LROW[r] = LROW[r] * alpha + psum;                                       \
        _Pragma("unroll")                                                       \
        for (int nd = 0; nd < 8; ++nd)                                          \
          OACC[nd][r] *= alpha;                                                 \
      }                                                                         \
    }                                                                           \
    _Pragma("unroll")                                                           \
    for (int n = 0; n < 4; ++n) {                                               \
      const int colb = (n * 16 + cl) * 2;                                       \
      _Pragma("unroll")                                                         \
      for (int r = 0; r < 4; ++r) {                                             \
        const int row = rbase + r;                                              \
        *(__bf16*)(Pb + row * 128 + (colb ^ ((row & 7) << 4))) = (__bf16)sacc[n][r]; \
      }                                                                         \
    }                                                                           \
    _Pragma("unroll")                                                           \
    for (int kk = 0; kk < 2; ++kk) {                                            \
      bf16x8 pa, bv[8];                                                         \
      {                                                                         \
        int row = cl;                                                           \
        int cb = (kk * 64 + ((lane >> 4) << 4)) ^ ((row & 7) << 4);             \
        pa = *(const bf16x8*)(Pb + row * 128 + cb);                             \
      }                                                                         \
      _Pragma("unroll")                                                         \
      for (int nd = 0; nd < 8; ++nd) {                                          \
        int row = nd * 16 + cl;                                                 \
        int cb = (kk * 64 + ((lane >> 4) << 4)) ^ ((row & 7) << 4);             \
        bv[nd] = *(const bf16x8*)(Vb + row * 128 + cb);                         \
      }                                                                         \
      __builtin_amdgcn_s_setprio(1);                                            \
      _Pragma("unroll")                                                         \
      for (int nd = 0; nd < 8; ++nd)                                            \
        OACC[nd] = __builtin_amdgcn_mfma_f32_16x16x32_bf16(pa, bv[nd], OACC[nd], 0, 0, 0); \
      __builtin_amdgcn_s_setprio(0);                                            \
    }                                                                           \
  }

__global__ __launch_bounds__(256, 2)
void attn_kernel(const __bf16* __restrict__ q, const __bf16* __restrict__ k,
                 const __bf16* __restrict__ vt, __bf16* __restrict__ ctx) {
  const int flat = blockIdx.x;
  const int swz = (flat & 7) * 64 + (flat >> 3);   // bijective (512 % 8 == 0)
  const int p = swz & 15;                          // q-pair index
  const int h = swz >> 4;                          // head: 4 heads per XCD chunk
  const int tid = threadIdx.x, lane = tid & 63, wave = tid >> 6;
  __shared__ char Kd[2][16384];       // K [kv64][d128] bf16, 256B rows
  __shared__ char Vd[2][16384];       // V^T [d128][kv64] bf16, 128B rows
  __shared__ __bf16 Ps[4][16 * 64];   // per-wave P (16 q-rows x 64 kv), 128B rows
  char* Pb = (char*)(Ps[wave]);

  const __bf16* qh = q + (size_t)h * S_LEN * 128;
  const __bf16* kh = k + (size_t)h * S_LEN * 128;
  const __bf16* vh = vt + (size_t)h * 128 * S_LEN;

  const int cl = lane & 15, rbase = (lane >> 4) << 2;

  const int krow = tid >> 4, kcol = (tid & 15) * 16;
  const int kcs = kcol ^ ((krow & 7) << 4);
  const int vrow = tid >> 3, vcol = (tid & 7) * 16;
  const int vcs = vcol ^ ((vrow & 7) << 4);

  auto stage_kv = [&](int j) {
    {
      const char* src = (const char*)(kh + (size_t)(j * 64 + krow) * 128) + kcs;
      char* dst = Kd[j & 1] + wave * 1024;
#pragma unroll
      for (int i = 0; i < 4; ++i)
        gl_lds16(src + (size_t)i * 16 * 256, dst + i * 4096);
    }
    {
      const char* src = (const char*)(vh + (size_t)vrow * S_LEN + j * 64) + vcs;
      char* dst = Vd[j & 1] + wave * 1024;
#pragma unroll
      for (int i = 0; i < 4; ++i)
        gl_lds16(src + (size_t)i * 32 * (S_LEN * 2), dst + i * 4096);
    }
  };

  const int qtA = p, qtB = 31 - p;

  bf16x8 qfA[4], qfB[4];
  {
    const int rA = qtA * 64 + wave * 16 + cl;
    const int rB = qtB * 64 + wave * 16 + cl;
#pragma unroll
    for (int kk = 0; kk < 4; ++kk) {
      qfA[kk] = *(const bf16x8*)(qh + (size_t)rA * 128 + kk * 32 + ((lane >> 4) << 3));
      qfB[kk] = *(const bf16x8*)(qh + (size_t)rB * 128 + kk * 32 + ((lane >> 4) << 3));
    }
  }

  f32x4 oA[8] = {}, oB[8] = {};
  float mA[4], lA[4], mB[4], lB[4];
#pragma unroll
  for (int r = 0; r < 4; ++r) { mA[r] = -1e30f; lA[r] = 0.f; mB[r] = -1e30f; lB[r] = 0.f; }

  stage_kv(0);
  __syncthreads();
  for (int j = 0; j <= qtB; ++j) {
    if (j < qtB) stage_kv(j + 1);   // prefetch buf^1, hides under compute(s)
    const char* Kb = Kd[j & 1];
    const char* Vb = Vd[j & 1];
    ATTN_PROCESS(qfB, oB, mB, lB, qtB)
    if (j <= qtA) ATTN_PROCESS(qfA, oA, mA, lA, qtA)
    __syncthreads();
  }

  // epilogues
#pragma unroll
  for (int nd = 0; nd < 8; ++nd) {
    const int d = nd * 16 + cl;
#pragma unroll
    for (int r = 0; r < 4; ++r) {
      const int srowA = qtA * 64 + wave * 16 + rbase + r;
      const int srowB = qtB * 64 + wave * 16 + rbase + r;
      ctx[(size_t)srowA * HID + h * 128 + d] = (__bf16)(oA[nd][r] / lA[r]);
      ctx[(size_t)srowB * HID + h * 128 + d] = (__bf16)(oB[nd][r] / lB[r]);
    }
  }
}

extern "C" void kernel_launch(void* const* d_in, const int* in_sizes, int n_in,
                              void* d_out, int out_size, void* d_ws, size_t ws_size,
                              hipStream_t stream) {
  const float* hs = (const float*)d_in[0];
  const int* pos = (const int*)d_in[1];
  const float* wqkv = (const float*)d_in[3];
  const float* bqkv = (const float*)d_in[4];
  const float* wd = (const float*)d_in[5];
  const float* bd = (const float*)d_in[6];
  float* out = (float*)d_out;

  char* ws = (char*)d_ws;
  const size_t MB = 1024ull * 1024ull;
  if (ws_size < 160 * MB) return;   // need 160MB scratch
  __bf16* wT  = (__bf16*)(ws);             // 96MB: wqkv^T bf16 [12288][4096]; later wdense^T
  __bf16* xb  = (__bf16*)(ws + 96 * MB);   // 16MB: x bf16; later ctx bf16
  __bf16* qb_ = (__bf16*)(ws + 112 * MB);  // 16MB: q [NH][S][D]
  __bf16* kb_ = (__bf16*)(ws + 128 * MB);  // 16MB: k [NH][S][D]
  __bf16* vtb = (__bf16*)(ws + 144 * MB);  // 16MB: v^T [NH][D][S]

  cvt_f32_bf16<<<8192, 256, 0, stream>>>(hs, xb, 2097152);
  transpose_cvt<<<dim3(192, 64), 256, 0, stream>>>(wqkv, wT, 4096, 12288);
  gemm32<0><<<768, 256, 0, stream>>>(xb, wT, bqkv, 4096, qb_, kb_, vtb);
  rope_kernel<<<16384, 256, 0, stream>>>(qb_, kb_, pos);
  transpose_cvt<<<dim3(64, 64), 256, 0, stream>>>(wd, wT, 4096, 4096);
  attn_kernel<<<512, 256, 0, stream>>>(qb_, kb_, vtb, xb);
  gemm_dense<<<512, 256, 0, stream>>>(xb, wT, bd, 4096, out);
}